// Round 21
// baseline (188.757 us; speedup 1.0000x reference)
//
#include <hip/hip_runtime.h>
#include <hip/hip_bf16.h>

#define Bb 2
#define Ss 2048
#define Dd 1024
#define Hh 16
#define HDd 64
#define Mm (Bb*Ss)      // 4096
#define N3 (3*Dd)       // 3072

typedef __attribute__((ext_vector_type(8))) __bf16 bf16x8;
typedef __attribute__((ext_vector_type(4))) float f32x4;
typedef __attribute__((ext_vector_type(16))) float f32x16;
typedef __attribute__((ext_vector_type(8))) short short8;

__device__ __forceinline__ unsigned short f2b(float f) {
  unsigned int u = __float_as_uint(f);
  return (unsigned short)((u + 0x7fffu + ((u >> 16) & 1u)) >> 16);
}

__device__ __forceinline__ f32x4 mfma16(bf16x8 a, bf16x8 b, f32x4 c) {
  return __builtin_amdgcn_mfma_f32_16x16x32_bf16(a, b, c, 0, 0, 0);
}
__device__ __forceinline__ f32x16 mfma32(bf16x8 a, bf16x8 b, f32x16 c) {
  return __builtin_amdgcn_mfma_f32_32x32x16_bf16(a, b, c, 0, 0, 0);
}
__device__ __forceinline__ unsigned cvtpk(float lo, float hi) {
  unsigned r; asm("v_cvt_pk_bf16_f32 %0, %1, %2" : "=v"(r) : "v"(lo), "v"(hi)); return r;
}
// single-instruction 2^x (inputs pre-scaled by log2e, bounded -> no fixup needed)
__device__ __forceinline__ float fexp2(float x) {
  float r; asm("v_exp_f32 %0, %1" : "=v"(r) : "v"(x)); return r;
}
// async global->LDS, 16B per lane; LDS dest = uniform base + lane*16 (HW rule)
__device__ __forceinline__ void gload16(const unsigned short* g, unsigned short* l) {
  __builtin_amdgcn_global_load_lds((const __attribute__((address_space(1))) void*)g,
                                   (__attribute__((address_space(3))) void*)l, 16, 0, 0);
}

// ---------------- prep: LayerNorm + both weight casts (merged) ----------------
__global__ __launch_bounds__(256) void prep_kernel(const float* __restrict__ x,
                                                   const float* __restrict__ gamma,
                                                   const float* __restrict__ beta,
                                                   unsigned short* __restrict__ xn,
                                                   const float* __restrict__ w_in,
                                                   unsigned short* __restrict__ wqkv,
                                                   const float* __restrict__ w_out,
                                                   unsigned short* __restrict__ wout) {
  const int bid = blockIdx.x, t = threadIdx.x;
  if (bid < Mm) {
    const float* xr = x + (size_t)bid * Dd;
    float4 v = ((const float4*)xr)[t];
    float s  = v.x + v.y + v.z + v.w;
    float ss = v.x*v.x + v.y*v.y + v.z*v.z + v.w*v.w;
    for (int m = 1; m < 64; m <<= 1) { s += __shfl_xor(s, m, 64); ss += __shfl_xor(ss, m, 64); }
    __shared__ float rs[4], rss[4];
    int w = t >> 6;
    if ((t & 63) == 0) { rs[w] = s; rss[w] = ss; }
    __syncthreads();
    s  = rs[0] + rs[1] + rs[2] + rs[3];
    ss = rss[0] + rss[1] + rss[2] + rss[3];
    float mu   = s * (1.0f / Dd);
    float var  = ss * (1.0f / Dd) - mu * mu;
    float rstd = rsqrtf(var + 1e-5f);
    float4 g  = ((const float4*)gamma)[t];
    float4 be = ((const float4*)beta)[t];
    ushort4 o;
    o.x = f2b((v.x - mu) * rstd * g.x + be.x);
    o.y = f2b((v.y - mu) * rstd * g.y + be.y);
    o.z = f2b((v.z - mu) * rstd * g.z + be.z);
    o.w = f2b((v.w - mu) * rstd * g.w + be.w);
    ((ushort4*)(xn + (size_t)bid * Dd))[t] = o;
  } else if (bid < Mm + 1024) {
    const int b2 = bid - Mm;
    for (int i = b2*256 + t; i < (N3*Dd)/4; i += 1024*256) {
      float4 v = ((const float4*)w_in)[i];
      ushort4 u; u.x = f2b(v.x); u.y = f2b(v.y); u.z = f2b(v.z); u.w = f2b(v.w);
      ((ushort4*)wqkv)[i] = u;
    }
  } else {
    const int b2 = bid - Mm - 1024;
    for (int i = b2*256 + t; i < (Dd*Dd)/4; i += 512*256) {
      float4 v = ((const float4*)w_out)[i];
      ushort4 u; u.x = f2b(v.x); u.y = f2b(v.y); u.z = f2b(v.z); u.w = f2b(v.w);
      ((ushort4*)wout)[i] = u;
    }
  }
}

// ---------------- QKV GEMM: BM=64 BN=128 BK=64, 6 blocks/CU, XCD swizzle -------
__global__ __launch_bounds__(256) void qkv_gemm_kernel(
    const unsigned short* __restrict__ A, const unsigned short* __restrict__ Bw,
    const float* __restrict__ bias,
    unsigned short* __restrict__ qb, unsigned short* __restrict__ kb,
    unsigned short* __restrict__ vtb) {
  __shared__ __align__(16) unsigned short As[64][64];    // 8 KB
  __shared__ __align__(16) unsigned short Bs[128][64];   // 16 KB
  const int t = threadIdx.x, l = t & 63, w = t >> 6;
  const int wr = w >> 1, wc = w & 1;
  const int lin = blockIdx.x;
  const int swz = (lin & 7) * 192 + (lin >> 3);
  const int mb = (swz & 63) * 64, nb = (swz >> 6) * 128;
  const int sc8 = ((l & 7) ^ ((l >> 3) & 7)) * 8;    // pre-swizzled source col
  f32x4 acc[2][4];
  for (int i = 0; i < 2; i++) for (int j = 0; j < 4; j++) acc[i][j] = f32x4{0.f,0.f,0.f,0.f};
  for (int kt = 0; kt < 1024; kt += 64) {
    __syncthreads();
#pragma unroll
    for (int j = 0; j < 2; ++j) {          // A: 64 rows, warp covers 16
      int rbase = w*16 + j*8;
      gload16(&A[(size_t)(mb + rbase + (l >> 3))*1024 + kt + sc8], &As[rbase][0]);
    }
#pragma unroll
    for (int j = 0; j < 4; ++j) {          // B: 128 rows, warp covers 32
      int rbase = w*32 + j*8;
      gload16(&Bw[(size_t)(nb + rbase + (l >> 3))*1024 + kt + sc8], &Bs[rbase][0]);
    }
    __syncthreads();
#pragma unroll
    for (int ks = 0; ks < 2; ++ks) {
      bf16x8 af[2], bfr[4];
      const int g = ks*4 + (l >> 4);
#pragma unroll
      for (int i = 0; i < 2; i++) {
        int row = wr*32 + i*16 + (l & 15);
        af[i] = *(const bf16x8*)&As[row][(g ^ (row & 7))*8];
      }
#pragma unroll
      for (int j = 0; j < 4; j++) {
        int row = wc*64 + j*16 + (l & 15);
        bfr[j] = *(const bf16x8*)&Bs[row][(g ^ (row & 7))*8];
      }
#pragma unroll
      for (int i = 0; i < 2; i++)
#pragma unroll
        for (int j = 0; j < 4; j++)
          acc[i][j] = mfma16(af[i], bfr[j], acc[i][j]);
    }
  }
  const int rbase = (l >> 4) * 4;
#pragma unroll
  for (int i = 0; i < 2; i++) {
#pragma unroll
    for (int j = 0; j < 4; j++) {
      int ncol = nb + wc*64 + j*16 + (l & 15);
      int which = ncol >> 10, d = ncol & 1023, h = d >> 6, hd = d & 63;
      float bv = bias[ncol];
      int mrow0 = mb + wr*32 + i*16 + rbase;
      int b = mrow0 >> 11, s0 = mrow0 & 2047;
      if (which == 2) {
        ushort4 u;
        u.x = f2b(acc[i][j][0] + bv); u.y = f2b(acc[i][j][1] + bv);
        u.z = f2b(acc[i][j][2] + bv); u.w = f2b(acc[i][j][3] + bv);
        *(ushort4*)&vtb[((size_t)(b*Hh + h)*HDd + hd)*Ss + s0] = u;
      } else {
        unsigned short* dst = (which == 0) ? qb : kb;
        float sc = (which == 0) ? 0.18033688f : 1.0f;   // 0.125*log2(e)
#pragma unroll
        for (int r = 0; r < 4; r++)
          dst[((size_t)(b*Hh + h)*Ss + s0 + r)*HDd + hd] = f2b((acc[i][j][r] + bv) * sc);
      }
    }
  }
}

// ---------------- ctx: 8-warp in-block K-split-2, dbuf gload_lds (R10 struct) --
__global__ __launch_bounds__(512) void ctx_kernel(const unsigned short* __restrict__ q,
                                                  const unsigned short* __restrict__ k,
                                                  const unsigned short* __restrict__ vt,
                                                  float* __restrict__ linv,
                                                  unsigned short* __restrict__ ctxb) {
  const int bh = blockIdx.x, qt = blockIdx.y;
  const int b = bh >> 4, h = bh & 15;
  const unsigned short* qp  = q  + (size_t)bh * Ss * HDd;
  const unsigned short* kp  = k  + (size_t)bh * Ss * HDd;
  const unsigned short* vtp = vt + (size_t)bh * HDd * Ss;
  const int t = threadIdx.x, l = t & 63, w = t >> 6;
  const int wq = w & 3, wk = w >> 2;          // q sub-tile / k half
  const int l31 = l & 31, hi = l >> 5;
  __shared__ __align__(16) unsigned short Ks[2][2][64][64];   // [wk][buf] 32 KB
  __shared__ __align__(16) unsigned short Vs[2][2][64][64];   // [wk][buf] 32 KB
  __shared__ float ls[8][32];
  const int qbase = qt*128 + wq*32;
  const int sc8 = ((l & 7) ^ ((l >> 3) & 7)) * 8;    // pre-swizzled source col
  const int kofs = wk * 1024;
  bf16x8 qfr[4];
#pragma unroll
  for (int c = 0; c < 4; ++c)
    qfr[c] = *(const bf16x8*)&qp[(size_t)(qbase + l31)*HDd + c*16 + hi*8];
  // prologue: stage tile 0 of this k-half
#pragma unroll
  for (int j = 0; j < 2; ++j) {
    int rbase = wq*16 + j*8;
    int row = rbase + (l >> 3);
    gload16(&kp [(size_t)(kofs + row)*HDd + sc8], &Ks[wk][0][rbase][0]);
    gload16(&vtp[(size_t)row*Ss + kofs + sc8],    &Vs[wk][0][rbase][0]);
  }
  __syncthreads();

  f32x16 cacc[2];
#pragma unroll
  for (int dj = 0; dj < 2; ++dj)
#pragma unroll
    for (int r = 0; r < 16; ++r) cacc[dj][r] = 0.f;
  float lsum = 0.f;

  for (int it = 0; it < 16; ++it) {
    const int cur = it & 1;
    if (it < 15) {
      int kt = kofs + (it + 1) * 64;
#pragma unroll
      for (int j = 0; j < 2; ++j) {
        int rbase = wq*16 + j*8;
        int row = rbase + (l >> 3);
        gload16(&kp [(size_t)(kt + row)*HDd + sc8], &Ks[wk][cur^1][rbase][0]);
        gload16(&vtp[(size_t)row*Ss + kt + sc8],    &Vs[wk][cur^1][rbase][0]);
      }
    }
#pragma unroll
    for (int kj = 0; kj < 2; ++kj) {
      f32x16 sacc;
#pragma unroll
      for (int r = 0; r < 16; ++r) sacc[r] = 0.f;
      __builtin_amdgcn_s_setprio(1);
#pragma unroll
      for (int c = 0; c < 4; ++c) {
        int R = kj*32 + l31;
        int s = 2*c + hi;
        bf16x8 kf = *(const bf16x8*)&Ks[wk][cur][R][(s ^ (R & 7))*8];
        sacc = mfma32(kf, qfr[c], sacc);
      }
      __builtin_amdgcn_s_setprio(0);
      float p[16];
#pragma unroll
      for (int r = 0; r < 16; ++r) { p[r] = fexp2(sacc[r]); lsum += p[r]; }
      unsigned xa = cvtpk(p[0],p[1]),   xb = cvtpk(p[4],p[5]);
      unsigned ya = cvtpk(p[2],p[3]),   yb = cvtpk(p[6],p[7]);
      unsigned za = cvtpk(p[8],p[9]),   zb = cvtpk(p[12],p[13]);
      unsigned wa = cvtpk(p[10],p[11]), wb = cvtpk(p[14],p[15]);
      asm volatile("v_permlane32_swap_b32 %0, %1" : "+v"(xa), "+v"(xb));
      asm volatile("v_permlane32_swap_b32 %0, %1" : "+v"(ya), "+v"(yb));
      asm volatile("v_permlane32_swap_b32 %0, %1" : "+v"(za), "+v"(zb));
      asm volatile("v_permlane32_swap_b32 %0, %1" : "+v"(wa), "+v"(wb));
      union { unsigned u[4]; bf16x8 v; } f0, f1;
      f0.u[0]=xa; f0.u[1]=ya; f0.u[2]=xb; f0.u[3]=yb;
      f1.u[0]=za; f1.u[1]=wa; f1.u[2]=zb; f1.u[3]=wb;
      __builtin_amdgcn_s_setprio(1);
#pragma unroll
      for (int kc = 0; kc < 2; ++kc) {
        bf16x8 pa = kc ? f1.v : f0.v;
#pragma unroll
        for (int dj = 0; dj < 2; ++dj) {
          int Rv = dj*32 + l31;
          int s = 4*kj + 2*kc + hi;
          bf16x8 vb = *(const bf16x8*)&Vs[wk][cur][Rv][(s ^ (Rv & 7))*8];
          cacc[dj] = mfma32(pa, vb, cacc[dj]);
        }
      }
      __builtin_amdgcn_s_setprio(0);
    }
    __syncthreads();
  }
  // ---- combine the two k-halves ----
  lsum += __shfl_xor(lsum, 32, 64);
  if (l < 32) ls[w][l] = lsum;
  float* scr = (float*)&Ks[0][0][0][0];    // 32 KB scratch (loop done with Ks)
  if (wk == 1) {
#pragma unroll
    for (int dj = 0; dj < 2; ++dj)
#pragma unroll
      for (int r = 0; r < 16; ++r)
        scr[((wq*2 + dj)*16 + r)*64 + l] = cacc[dj][r];
  }
  __syncthreads();
  if (wk == 0) {
#pragma unroll
    for (int dj = 0; dj < 2; ++dj)
#pragma unroll
      for (int r = 0; r < 16; ++r)
        cacc[dj][r] += scr[((wq*2 + dj)*16 + r)*64 + l];
    if (l < 32) {
      float li = 1.0f / (ls[w][l] + ls[w + 4][l]);
      ls[w][l] = li;
      linv[(size_t)bh*Ss + qbase + l] = li;
    }
    float li4[4][4];
#pragma unroll
    for (int g = 0; g < 4; ++g) {
      f32x4 v4 = *(const f32x4*)&ls[w][8*g + 4*hi];
#pragma unroll
      for (int j = 0; j < 4; ++j) li4[g][j] = v4[j];
    }
#pragma unroll
    for (int dj = 0; dj < 2; ++dj) {
      int d = h*64 + dj*32 + l31;
#pragma unroll
      for (int r = 0; r < 16; ++r) {
        int qq = qbase + (r & 3) + 8*(r >> 2) + 4*hi;
        ctxb[((size_t)b*Ss + qq)*Dd + d] = f2b(cacc[dj][r] * li4[r >> 2][r & 3]);
      }
    }
  }
}

// ---------------- merged uniform block: attnw(128x64) + out(128x32) ------------
// 1024 identical blocks; bid&1 picks phase order so CUs host a mix of phases.
union SharedU {
  struct { unsigned short qbuf[128][64]; unsigned short kbuf[64][64]; } g;  // attnw: 24 KB
  float ps[64][66];                                                         // 16.9 KB overlay
  struct { unsigned short As[128][64]; unsigned short Bs[32][64]; } o;      // out:   20 KB
};

__device__ __forceinline__ void attnw_part(SharedU& L,
    const unsigned short* __restrict__ q, const unsigned short* __restrict__ k,
    const float* __restrict__ linv, float* __restrict__ attw, int lin) {
  const int t = threadIdx.x, l = t & 63, w = t >> 6;
  const int xcd = lin & 7, j0 = lin >> 3;
  const int ktile = (xcd & 3)*8 + (j0 & 7);
  const int qt    = (xcd >> 2)*8 + ((j0 >> 3) & 7);
  const int b     = j0 >> 6;
  const int l31 = l & 31, hi = l >> 5;
  const int qbase = qt*128 + w*32;
  const int qrow = qbase + l31;
  const int sc8 = ((l & 7) ^ ((l >> 3) & 7)) * 8;

  float psum[2][16];
#pragma unroll
  for (int kj = 0; kj < 2; ++kj)
#pragma unroll
    for (int r = 0; r < 16; ++r) psum[kj][r] = 0.f;

#pragma unroll 1
  for (int h = 0; h < 16; ++h) {
    __syncthreads();   // previous compute done; safe to overwrite buffers
    const unsigned short* qp = q + ((size_t)(b*Hh + h)*Ss + (size_t)qt*128)*HDd;
    const unsigned short* kp = k + ((size_t)(b*Hh + h)*Ss + (size_t)ktile*64)*HDd;
#pragma unroll
    for (int j = 0; j < 4; ++j) {        // Q: 128 rows, warp covers 32
      int rbase = w*32 + j*8;
      gload16(&qp[(size_t)(rbase + (l >> 3))*HDd + sc8], &L.g.qbuf[rbase][0]);
    }
#pragma unroll
    for (int j = 0; j < 2; ++j) {        // K: 64 rows, warp covers 16
      int rbase = w*16 + j*8;
      gload16(&kp[(size_t)(rbase + (l >> 3))*HDd + sc8], &L.g.kbuf[rbase][0]);
    }
    float li = linv[(size_t)(b*Hh + h)*Ss + qrow];
    __syncthreads();   // staging landed
    bf16x8 qfr[4];
#pragma unroll
    for (int c = 0; c < 4; ++c) {
      int row = w*32 + l31;
      int s = 2*c + hi;
      qfr[c] = *(const bf16x8*)&L.g.qbuf[row][(s ^ (row & 7))*8];
    }
#pragma unroll
    for (int kj = 0; kj < 2; ++kj) {
      f32x16 sacc;
#pragma unroll
      for (int r = 0; r < 16; ++r) sacc[r] = 0.f;
      __builtin_amdgcn_s_setprio(1);
#pragma unroll
      for (int c = 0; c < 4; ++c) {
        int R = kj*32 + l31;
        int s = 2*c + hi;
        bf16x8 kf = *(const bf16x8*)&L.g.kbuf[R][(s ^ (R & 7))*8];
        sacc = mfma32(kf, qfr[c], sacc);
      }
      __builtin_amdgcn_s_setprio(0);
#pragma unroll
      for (int r = 0; r < 16; ++r) psum[kj][r] += fexp2(sacc[r]) * li;
    }
  }

  // epilogue: two 64-row transpose passes through the 16.9 KB ps overlay
#pragma unroll
  for (int p = 0; p < 2; ++p) {
    __syncthreads();
    if ((w >> 1) == p) {
#pragma unroll
      for (int kj = 0; kj < 2; ++kj)
#pragma unroll
        for (int r = 0; r < 16; ++r) {
          int krow = kj*32 + (r & 3) + 8*(r >> 2) + 4*hi;
          L.ps[(w & 1)*32 + l31][krow] = psum[kj][r] * (1.0f/16.0f);
        }
    }
    __syncthreads();
#pragma unroll
    for (int pass = 0; pass < 4; ++pass) {
      int row = pass*16 + (t >> 4), c4 = (t & 15) * 4;
      float4 v = *(const float4*)&L.ps[row][c4];
      *(float4*)&attw[((size_t)b*Ss + qt*128 + p*64 + row)*Ss + (size_t)ktile*64 + c4] = v;
    }
  }
}

__device__ __forceinline__ void out_part(SharedU& L,
    const unsigned short* __restrict__ ctxb, const unsigned short* __restrict__ wout,
    const float* __restrict__ bias, const float* __restrict__ x,
    float* __restrict__ outp, int ob) {
  const int t = threadIdx.x, l = t & 63, w = t >> 6;
  const int wr = w >> 1, wc = w & 1;
  const int mb = (ob & 31) * 128, nb = (ob >> 5) * 32;
  const int sc8 = ((l & 7) ^ ((l >> 3) & 7)) * 8;
  f32x4 acc[4];
  for (int i = 0; i < 4; i++) acc[i] = f32x4{0.f,0.f,0.f,0.f};
  for (int kt = 0; kt < 1024; kt += 64) {
    __syncthreads();
#pragma unroll
    for (int j = 0; j < 4; ++j) {          // A: 128 rows, warp covers 32
      int rbase = w*32 + j*8;
      int row = rbase + (l >> 3);
      gload16(&ctxb[(size_t)(mb + row)*1024 + kt + sc8], &L.o.As[rbase][0]);
    }
    {                                      // B: 32 rows, warp covers 8
      int rbase = w*8;
      int row = rbase + (l >> 3);
      gload16(&wout[(size_t)(nb + row)*1024 + kt + sc8], &L.o.Bs[rbase][0]);
    }
    __syncthreads();
#pragma unroll
    for (int ks = 0; ks < 2; ++ks) {
      bf16x8 af[4], bfr;
      const int g = ks*4 + (l >> 4);
#pragma unroll
      for (int i = 0; i < 4; i++) {
        int row = wr*64 + i*16 + (l & 15);
        af[i] = *(const bf16x8*)&L.o.As[row][(g ^ (row & 7))*8];
      }
      {
        int row = wc*16 + (l & 15);
        bfr = *(const bf16x8*)&L.o.Bs[row][(g ^ (row & 7))*8];
      }
#pragma unroll
      for (int i = 0; i < 4; i++)
        acc[i] = mfma16(af[i], bfr, acc[i]);
    }
  }
  const int rbase = (l >> 4) * 4;
#pragma unroll
  for (int i = 0; i < 4; i++) {
    int ncol = nb + wc*16 + (l & 15);
    float bv = bias[ncol];
#pragma unroll
    for (int r = 0; r < 4; r++) {
      int mrow = mb + wr*64 + i*16 + rbase + r;
      size_t idx = (size_t)mrow * 1024 + ncol;
      outp[idx] = acc[i][r] + bv + x[idx];
    }
  }
}

__global__ __launch_bounds__(256) void attnw_out_kernel(
    const unsigned short* __restrict__ q, const unsigned short* __restrict__ k,
    const float* __restrict__ linv, float* __restrict__ attw,
    const unsigned short* __restrict__ ctxb, const unsigned short* __restrict__ wout,
    const float* __restrict__ bias, const float* __restrict__ x,
    float* __restrict__ outp) {
  __shared__ SharedU L;
  const int bid = blockIdx.x;
  if (bid & 1) {
    out_part(L, ctxb, wout, bias, x, outp, bid);
    attnw_part(L, q, k, linv, attw, bid);
  } else {
    attnw_part(L, q, k, linv, attw, bid);
    out_part(L, ctxb, wout, bias, x, outp, bid);
  }
}

extern "C" void kernel_launch(void* const* d_in, const int* in_sizes, int n_in,
                              void* d_out, int out_size, void* d_ws, size_t ws_size,
                              hipStream_t stream) {
  const float* x     = (const float*)d_in[0];
  const float* gamma = (const float*)d_in[2];
  const float* beta  = (const float*)d_in[3];
  const float* w_in  = (const float*)d_in[4];
  const float* b_in  = (const float*)d_in[5];
  const float* w_out = (const float*)d_in[6];
  const float* b_out = (const float*)d_in[7];
  float* outp = (float*)d_out;                     // [4096][1024]
  float* attw = outp + (size_t)Mm * Dd;            // [2][2048][2048]

  char* ws = (char*)d_ws;
  unsigned short* xn   = (unsigned short*)(ws + 0);          // 8 MB
  unsigned short* wqkv = (unsigned short*)(ws + 8388608);    // 6 MB
  unsigned short* wout = (unsigned short*)(ws + 14680064);   // 2 MB
  unsigned short* qb   = (unsigned short*)(ws + 16777216);   // 8 MB  [b][h][s][hd], pre-scaled 0.125*log2e
  unsigned short* kb   = (unsigned short*)(ws + 25165824);   // 8 MB  [b][h][s][hd]
  unsigned short* vtb  = (unsigned short*)(ws + 33554432);   // 8 MB  [b][h][hd][s]
  float*          linv = (float*)(ws + 41943040);            // 256 KB
  unsigned short* ctxb = (unsigned short*)(ws + 42205184);   // 8 MB  [b][s][d]

  prep_kernel<<<Mm + 1024 + 512, 256, 0, stream>>>(x, gamma, beta, xn, w_in, wqkv, w_out, wout);
  qkv_gemm_kernel<<<(Mm/64)*(N3/128), 256, 0, stream>>>(xn, wqkv, b_in, qb, kb, vtb);
  ctx_kernel<<<dim3(Bb*Hh, Ss/128), 512, 0, stream>>>(qb, kb, vtb, linv, ctxb);
  attnw_out_kernel<<<1024, 256, 0, stream>>>(qb, kb, linv, attw, ctxb, wout, b_out, x, outp);
}

// Round 22
// 136.727 us; speedup vs baseline: 1.3805x; 1.3805x over previous
//
#include <hip/hip_runtime.h>
#include <hip/hip_bf16.h>

#define Bb 2
#define Ss 2048
#define Dd 1024
#define Hh 16
#define HDd 64
#define Mm (Bb*Ss)      // 4096
#define N3 (3*Dd)       // 3072

typedef __attribute__((ext_vector_type(8))) __bf16 bf16x8;
typedef __attribute__((ext_vector_type(4))) float f32x4;
typedef __attribute__((ext_vector_type(16))) float f32x16;
typedef __attribute__((ext_vector_type(8))) short short8;

__device__ __forceinline__ unsigned short f2b(float f) {
  unsigned int u = __float_as_uint(f);
  return (unsigned short)((u + 0x7fffu + ((u >> 16) & 1u)) >> 16);
}

__device__ __forceinline__ f32x4 mfma16(bf16x8 a, bf16x8 b, f32x4 c) {
  return __builtin_amdgcn_mfma_f32_16x16x32_bf16(a, b, c, 0, 0, 0);
}
__device__ __forceinline__ f32x16 mfma32(bf16x8 a, bf16x8 b, f32x16 c) {
  return __builtin_amdgcn_mfma_f32_32x32x16_bf16(a, b, c, 0, 0, 0);
}
__device__ __forceinline__ unsigned cvtpk(float lo, float hi) {
  unsigned r; asm("v_cvt_pk_bf16_f32 %0, %1, %2" : "=v"(r) : "v"(lo), "v"(hi)); return r;
}
// single-instruction 2^x (inputs pre-scaled by log2e, bounded -> no fixup needed)
__device__ __forceinline__ float fexp2(float x) {
  float r; asm("v_exp_f32 %0, %1" : "=v"(r) : "v"(x)); return r;
}
// async global->LDS, 16B per lane; LDS dest = uniform base + lane*16 (HW rule)
__device__ __forceinline__ void gload16(const unsigned short* g, unsigned short* l) {
  __builtin_amdgcn_global_load_lds((const __attribute__((address_space(1))) void*)g,
                                   (__attribute__((address_space(3))) void*)l, 16, 0, 0);
}

// ---------------- prep: LayerNorm + both weight casts (merged) ----------------
__global__ __launch_bounds__(256) void prep_kernel(const float* __restrict__ x,
                                                   const float* __restrict__ gamma,
                                                   const float* __restrict__ beta,
                                                   unsigned short* __restrict__ xn,
                                                   const float* __restrict__ w_in,
                                                   unsigned short* __restrict__ wqkv,
                                                   const float* __restrict__ w_out,
                                                   unsigned short* __restrict__ wout) {
  const int bid = blockIdx.x, t = threadIdx.x;
  if (bid < Mm) {
    const float* xr = x + (size_t)bid * Dd;
    float4 v = ((const float4*)xr)[t];
    float s  = v.x + v.y + v.z + v.w;
    float ss = v.x*v.x + v.y*v.y + v.z*v.z + v.w*v.w;
    for (int m = 1; m < 64; m <<= 1) { s += __shfl_xor(s, m, 64); ss += __shfl_xor(ss, m, 64); }
    __shared__ float rs[4], rss[4];
    int w = t >> 6;
    if ((t & 63) == 0) { rs[w] = s; rss[w] = ss; }
    __syncthreads();
    s  = rs[0] + rs[1] + rs[2] + rs[3];
    ss = rss[0] + rss[1] + rss[2] + rss[3];
    float mu   = s * (1.0f / Dd);
    float var  = ss * (1.0f / Dd) - mu * mu;
    float rstd = rsqrtf(var + 1e-5f);
    float4 g  = ((const float4*)gamma)[t];
    float4 be = ((const float4*)beta)[t];
    ushort4 o;
    o.x = f2b((v.x - mu) * rstd * g.x + be.x);
    o.y = f2b((v.y - mu) * rstd * g.y + be.y);
    o.z = f2b((v.z - mu) * rstd * g.z + be.z);
    o.w = f2b((v.w - mu) * rstd * g.w + be.w);
    ((ushort4*)(xn + (size_t)bid * Dd))[t] = o;
  } else if (bid < Mm + 1024) {
    const int b2 = bid - Mm;
    for (int i = b2*256 + t; i < (N3*Dd)/4; i += 1024*256) {
      float4 v = ((const float4*)w_in)[i];
      ushort4 u; u.x = f2b(v.x); u.y = f2b(v.y); u.z = f2b(v.z); u.w = f2b(v.w);
      ((ushort4*)wqkv)[i] = u;
    }
  } else {
    const int b2 = bid - Mm - 1024;
    for (int i = b2*256 + t; i < (Dd*Dd)/4; i += 512*256) {
      float4 v = ((const float4*)w_out)[i];
      ushort4 u; u.x = f2b(v.x); u.y = f2b(v.y); u.z = f2b(v.z); u.w = f2b(v.w);
      ((ushort4*)wout)[i] = u;
    }
  }
}

// ---------------- QKV GEMM: BM=64 BN=128 BK=64, 6 blocks/CU, XCD swizzle -------
// q written pre-scaled by 0.125*log2(e) (for v_exp_f32 softmax); v transposed [b][h][hd][s]
__global__ __launch_bounds__(256) void qkv_gemm_kernel(
    const unsigned short* __restrict__ A, const unsigned short* __restrict__ Bw,
    const float* __restrict__ bias,
    unsigned short* __restrict__ qb, unsigned short* __restrict__ kb,
    unsigned short* __restrict__ vtb) {
  __shared__ __align__(16) unsigned short As[64][64];    // 8 KB
  __shared__ __align__(16) unsigned short Bs[128][64];   // 16 KB
  const int t = threadIdx.x, l = t & 63, w = t >> 6;
  const int wr = w >> 1, wc = w & 1;
  // bijective XCD swizzle: 1536 blocks, each XCD gets 192 consecutive (3 B-panels)
  const int lin = blockIdx.x;
  const int swz = (lin & 7) * 192 + (lin >> 3);
  const int mb = (swz & 63) * 64, nb = (swz >> 6) * 128;
  const int sc8 = ((l & 7) ^ ((l >> 3) & 7)) * 8;    // pre-swizzled source col
  f32x4 acc[2][4];
  for (int i = 0; i < 2; i++) for (int j = 0; j < 4; j++) acc[i][j] = f32x4{0.f,0.f,0.f,0.f};
  for (int kt = 0; kt < 1024; kt += 64) {
    __syncthreads();
#pragma unroll
    for (int j = 0; j < 2; ++j) {          // A: 64 rows, warp covers 16
      int rbase = w*16 + j*8;
      gload16(&A[(size_t)(mb + rbase + (l >> 3))*1024 + kt + sc8], &As[rbase][0]);
    }
#pragma unroll
    for (int j = 0; j < 4; ++j) {          // B: 128 rows, warp covers 32
      int rbase = w*32 + j*8;
      gload16(&Bw[(size_t)(nb + rbase + (l >> 3))*1024 + kt + sc8], &Bs[rbase][0]);
    }
    __syncthreads();
#pragma unroll
    for (int ks = 0; ks < 2; ++ks) {
      bf16x8 af[2], bfr[4];
      const int g = ks*4 + (l >> 4);
#pragma unroll
      for (int i = 0; i < 2; i++) {
        int row = wr*32 + i*16 + (l & 15);
        af[i] = *(const bf16x8*)&As[row][(g ^ (row & 7))*8];
      }
#pragma unroll
      for (int j = 0; j < 4; j++) {
        int row = wc*64 + j*16 + (l & 15);
        bfr[j] = *(const bf16x8*)&Bs[row][(g ^ (row & 7))*8];
      }
#pragma unroll
      for (int i = 0; i < 2; i++)
#pragma unroll
        for (int j = 0; j < 4; j++)
          acc[i][j] = mfma16(af[i], bfr[j], acc[i][j]);
    }
  }
  const int rbase = (l >> 4) * 4;
#pragma unroll
  for (int i = 0; i < 2; i++) {
#pragma unroll
    for (int j = 0; j < 4; j++) {
      int ncol = nb + wc*64 + j*16 + (l & 15);
      int which = ncol >> 10, d = ncol & 1023, h = d >> 6, hd = d & 63;
      float bv = bias[ncol];
      int mrow0 = mb + wr*32 + i*16 + rbase;
      int b = mrow0 >> 11, s0 = mrow0 & 2047;
      if (which == 2) {
        ushort4 u;
        u.x = f2b(acc[i][j][0] + bv); u.y = f2b(acc[i][j][1] + bv);
        u.z = f2b(acc[i][j][2] + bv); u.w = f2b(acc[i][j][3] + bv);
        *(ushort4*)&vtb[((size_t)(b*Hh + h)*HDd + hd)*Ss + s0] = u;
      } else {
        unsigned short* dst = (which == 0) ? qb : kb;
        float sc = (which == 0) ? 0.18033688f : 1.0f;   // 0.125*log2(e)
#pragma unroll
        for (int r = 0; r < 4; r++)
          dst[((size_t)(b*Hh + h)*Ss + s0 + r)*HDd + hd] = f2b((acc[i][j][r] + bv) * sc);
      }
    }
  }
}

// ---------------- ctx: 8-warp in-block K-split-2, dbuf gload_lds (R10 struct) --
__global__ __launch_bounds__(512) void ctx_kernel(const unsigned short* __restrict__ q,
                                                  const unsigned short* __restrict__ k,
                                                  const unsigned short* __restrict__ vt,
                                                  float* __restrict__ linv,
                                                  unsigned short* __restrict__ ctxb) {
  const int bh = blockIdx.x, qt = blockIdx.y;
  const int b = bh >> 4, h = bh & 15;
  const unsigned short* qp  = q  + (size_t)bh * Ss * HDd;
  const unsigned short* kp  = k  + (size_t)bh * Ss * HDd;
  const unsigned short* vtp = vt + (size_t)bh * HDd * Ss;
  const int t = threadIdx.x, l = t & 63, w = t >> 6;
  const int wq = w & 3, wk = w >> 2;          // q sub-tile / k half
  const int l31 = l & 31, hi = l >> 5;
  __shared__ __align__(16) unsigned short Ks[2][2][64][64];   // [wk][buf] 32 KB
  __shared__ __align__(16) unsigned short Vs[2][2][64][64];   // [wk][buf] 32 KB
  __shared__ float ls[8][32];
  const int qbase = qt*128 + wq*32;
  const int sc8 = ((l & 7) ^ ((l >> 3) & 7)) * 8;    // pre-swizzled source col
  const int kofs = wk * 1024;
  bf16x8 qfr[4];
#pragma unroll
  for (int c = 0; c < 4; ++c)
    qfr[c] = *(const bf16x8*)&qp[(size_t)(qbase + l31)*HDd + c*16 + hi*8];
  // prologue: stage tile 0 of this k-half
#pragma unroll
  for (int j = 0; j < 2; ++j) {
    int rbase = wq*16 + j*8;
    int row = rbase + (l >> 3);
    gload16(&kp [(size_t)(kofs + row)*HDd + sc8], &Ks[wk][0][rbase][0]);
    gload16(&vtp[(size_t)row*Ss + kofs + sc8],    &Vs[wk][0][rbase][0]);
  }
  __syncthreads();

  f32x16 cacc[2];
#pragma unroll
  for (int dj = 0; dj < 2; ++dj)
#pragma unroll
    for (int r = 0; r < 16; ++r) cacc[dj][r] = 0.f;
  float lsum = 0.f;

  for (int it = 0; it < 16; ++it) {
    const int cur = it & 1;
    if (it < 15) {
      int kt = kofs + (it + 1) * 64;
#pragma unroll
      for (int j = 0; j < 2; ++j) {
        int rbase = wq*16 + j*8;
        int row = rbase + (l >> 3);
        gload16(&kp [(size_t)(kt + row)*HDd + sc8], &Ks[wk][cur^1][rbase][0]);
        gload16(&vtp[(size_t)row*Ss + kt + sc8],    &Vs[wk][cur^1][rbase][0]);
      }
    }
#pragma unroll
    for (int kj = 0; kj < 2; ++kj) {
      f32x16 sacc;
#pragma unroll
      for (int r = 0; r < 16; ++r) sacc[r] = 0.f;
      __builtin_amdgcn_s_setprio(1);
#pragma unroll
      for (int c = 0; c < 4; ++c) {
        int R = kj*32 + l31;
        int s = 2*c + hi;
        bf16x8 kf = *(const bf16x8*)&Ks[wk][cur][R][(s ^ (R & 7))*8];
        sacc = mfma32(kf, qfr[c], sacc);
      }
      __builtin_amdgcn_s_setprio(0);
      float p[16];
#pragma unroll
      for (int r = 0; r < 16; ++r) { p[r] = fexp2(sacc[r]); lsum += p[r]; }
      unsigned xa = cvtpk(p[0],p[1]),   xb = cvtpk(p[4],p[5]);
      unsigned ya = cvtpk(p[2],p[3]),   yb = cvtpk(p[6],p[7]);
      unsigned za = cvtpk(p[8],p[9]),   zb = cvtpk(p[12],p[13]);
      unsigned wa = cvtpk(p[10],p[11]), wb = cvtpk(p[14],p[15]);
      asm volatile("v_permlane32_swap_b32 %0, %1" : "+v"(xa), "+v"(xb));
      asm volatile("v_permlane32_swap_b32 %0, %1" : "+v"(ya), "+v"(yb));
      asm volatile("v_permlane32_swap_b32 %0, %1" : "+v"(za), "+v"(zb));
      asm volatile("v_permlane32_swap_b32 %0, %1" : "+v"(wa), "+v"(wb));
      union { unsigned u[4]; bf16x8 v; } f0, f1;
      f0.u[0]=xa; f0.u[1]=ya; f0.u[2]=xb; f0.u[3]=yb;
      f1.u[0]=za; f1.u[1]=wa; f1.u[2]=zb; f1.u[3]=wb;
      __builtin_amdgcn_s_setprio(1);
#pragma unroll
      for (int kc = 0; kc < 2; ++kc) {
        bf16x8 pa = kc ? f1.v : f0.v;
#pragma unroll
        for (int dj = 0; dj < 2; ++dj) {
          int Rv = dj*32 + l31;
          int s = 4*kj + 2*kc + hi;
          bf16x8 vb = *(const bf16x8*)&Vs[wk][cur][Rv][(s ^ (Rv & 7))*8];
          cacc[dj] = mfma32(pa, vb, cacc[dj]);
        }
      }
      __builtin_amdgcn_s_setprio(0);
    }
    __syncthreads();
  }
  // ---- combine the two k-halves ----
  lsum += __shfl_xor(lsum, 32, 64);
  if (l < 32) ls[w][l] = lsum;
  float* scr = (float*)&Ks[0][0][0][0];    // 32 KB scratch (loop done with Ks)
  if (wk == 1) {
#pragma unroll
    for (int dj = 0; dj < 2; ++dj)
#pragma unroll
      for (int r = 0; r < 16; ++r)
        scr[((wq*2 + dj)*16 + r)*64 + l] = cacc[dj][r];
  }
  __syncthreads();
  if (wk == 0) {
#pragma unroll
    for (int dj = 0; dj < 2; ++dj)
#pragma unroll
      for (int r = 0; r < 16; ++r)
        cacc[dj][r] += scr[((wq*2 + dj)*16 + r)*64 + l];
    if (l < 32) {
      float li = 1.0f / (ls[w][l] + ls[w + 4][l]);
      ls[w][l] = li;
      linv[(size_t)bh*Ss + qbase + l] = li;
    }
    float li4[4][4];
#pragma unroll
    for (int g = 0; g < 4; ++g) {
      f32x4 v4 = *(const f32x4*)&ls[w][8*g + 4*hi];
#pragma unroll
      for (int j = 0; j < 4; ++j) li4[g][j] = v4[j];
    }
#pragma unroll
    for (int dj = 0; dj < 2; ++dj) {
      int d = h*64 + dj*32 + l31;
#pragma unroll
      for (int r = 0; r < 16; ++r) {
        int qq = qbase + (r & 3) + 8*(r >> 2) + 4*hi;
        ctxb[((size_t)b*Ss + qq)*Dd + d] = f2b(cacc[dj][r] * li4[r >> 2][r & 3]);
      }
    }
  }
}

// ---------------- merged attnw + out_gemm: interleaved block mapping -----------
// bid%3 in {0,1} -> attnw block (1024 total); bid%3==2 -> out_gemm block (512).
// Every CU hosts a mix, so out's MFMA/VMEM fills attnw's barrier/VALU gaps.
__global__ __launch_bounds__(256) void attnw_out_kernel(
    const unsigned short* __restrict__ q, const unsigned short* __restrict__ k,
    const float* __restrict__ linv, float* __restrict__ attw,
    const unsigned short* __restrict__ ctxb, const unsigned short* __restrict__ wout,
    const float* __restrict__ bias, const float* __restrict__ x,
    float* __restrict__ outp) {
  __shared__ union __align__(16) {
    struct { unsigned short qbuf[128][64]; unsigned short kbuf[64][64]; } g;  // attnw: 24 KB
    float ps[128][68];                                                        // attnw: 34.8 KB
    struct { unsigned short As[128][64]; unsigned short Bs[64][64]; } o;      // out:   24 KB
  } L;
  const int t = threadIdx.x, l = t & 63, w = t >> 6;
  const int r3 = blockIdx.x % 3;
  if (r3 < 2) {
    // ======================= attn_w block =======================
    const int lin = (blockIdx.x / 3) * 2 + r3;   // 0..1023, XCD-locality swizzle
    const int xcd = lin & 7, j0 = lin >> 3;
    const int ktile = (xcd & 3)*8 + (j0 & 7);
    const int qt    = (xcd >> 2)*8 + ((j0 >> 3) & 7);
    const int b     = j0 >> 6;
    const int l31 = l & 31, hi = l >> 5;
    const int qbase = qt*128 + w*32;
    const int qrow = qbase + l31;
    const int sc8 = ((l & 7) ^ ((l >> 3) & 7)) * 8;

    float psum[2][16];
#pragma unroll
    for (int kj = 0; kj < 2; ++kj)
#pragma unroll
      for (int r = 0; r < 16; ++r) psum[kj][r] = 0.f;

#pragma unroll 1
    for (int h = 0; h < 16; ++h) {
      __syncthreads();   // previous head's compute done
      const unsigned short* qp = q + ((size_t)(b*Hh + h)*Ss + (size_t)qt*128)*HDd;
      const unsigned short* kp = k + ((size_t)(b*Hh + h)*Ss + (size_t)ktile*64)*HDd;
#pragma unroll
      for (int j = 0; j < 4; ++j) {        // Q: 128 rows, warp covers 32
        int rbase = w*32 + j*8;
        gload16(&qp[(size_t)(rbase + (l >> 3))*HDd + sc8], &L.g.qbuf[rbase][0]);
      }
#pragma unroll
      for (int j = 0; j < 2; ++j) {        // K: 64 rows, warp covers 16
        int rbase = w*16 + j*8;
        gload16(&kp[(size_t)(rbase + (l >> 3))*HDd + sc8], &L.g.kbuf[rbase][0]);
      }
      float li = linv[(size_t)(b*Hh + h)*Ss + qrow];
      __syncthreads();   // staging landed
      bf16x8 qfr[4];
#pragma unroll
      for (int c = 0; c < 4; ++c) {
        int row = w*32 + l31;
        int s = 2*c + hi;
        qfr[c] = *(const bf16x8*)&L.g.qbuf[row][(s ^ (row & 7))*8];
      }
#pragma unroll
      for (int kj = 0; kj < 2; ++kj) {
        f32x16 sacc;
#pragma unroll
        for (int r = 0; r < 16; ++r) sacc[r] = 0.f;
        __builtin_amdgcn_s_setprio(1);
#pragma unroll
        for (int c = 0; c < 4; ++c) {
          int R = kj*32 + l31;
          int s = 2*c + hi;
          bf16x8 kf = *(const bf16x8*)&L.g.kbuf[R][(s ^ (R & 7))*8];
          sacc = mfma32(kf, qfr[c], sacc);
        }
        __builtin_amdgcn_s_setprio(0);
#pragma unroll
        for (int r = 0; r < 16; ++r) psum[kj][r] += fexp2(sacc[r]) * li;
      }
    }

    // epilogue: transpose through overlaid LDS, then coalesced float4 row writes
    __syncthreads();
#pragma unroll
    for (int kj = 0; kj < 2; ++kj)
#pragma unroll
      for (int r = 0; r < 16; ++r) {
        int krow = kj*32 + (r & 3) + 8*(r >> 2) + 4*hi;
        L.ps[w*32 + l31][krow] = psum[kj][r] * (1.0f/16.0f);
      }
    __syncthreads();
#pragma unroll
    for (int pass = 0; pass < 8; ++pass) {
      int row = pass*16 + (t >> 4), c4 = (t & 15) * 4;
      float4 v = *(const float4*)&L.ps[row][c4];
      *(float4*)&attw[((size_t)b*Ss + qt*128 + row)*Ss + (size_t)ktile*64 + c4] = v;
    }
  } else {
    // ======================= out GEMM block =======================
    const int ob = blockIdx.x / 3;               // 0..511
    const int wr = w >> 1, wc = w & 1;
    const int mb = (ob & 31) * 128, nb = (ob >> 5) * 64;
    const int sc8 = ((l & 7) ^ ((l >> 3) & 7)) * 8;
    f32x4 acc[4][2];
    for (int i = 0; i < 4; i++) for (int j = 0; j < 2; j++) acc[i][j] = f32x4{0.f,0.f,0.f,0.f};
    for (int kt = 0; kt < 1024; kt += 64) {
      __syncthreads();
#pragma unroll
      for (int j = 0; j < 4; ++j) {
        int rbase = w*32 + j*8;
        int row = rbase + (l >> 3);
        gload16(&ctxb[(size_t)(mb + row)*1024 + kt + sc8], &L.o.As[rbase][0]);
      }
#pragma unroll
      for (int j = 0; j < 2; ++j) {
        int rbase = w*16 + j*8;
        int row = rbase + (l >> 3);
        gload16(&wout[(size_t)(nb + row)*1024 + kt + sc8], &L.o.Bs[rbase][0]);
      }
      __syncthreads();
#pragma unroll
      for (int ks = 0; ks < 2; ++ks) {
        bf16x8 af[4], bfr[2];
        const int g = ks*4 + (l >> 4);
#pragma unroll
        for (int i = 0; i < 4; i++) {
          int row = wr*64 + i*16 + (l & 15);
          af[i] = *(const bf16x8*)&L.o.As[row][(g ^ (row & 7))*8];
        }
#pragma unroll
        for (int j = 0; j < 2; j++) {
          int row = wc*32 + j*16 + (l & 15);
          bfr[j] = *(const bf16x8*)&L.o.Bs[row][(g ^ (row & 7))*8];
        }
#pragma unroll
        for (int i = 0; i < 4; i++)
#pragma unroll
          for (int j = 0; j < 2; j++)
            acc[i][j] = mfma16(af[i], bfr[j], acc[i][j]);
      }
    }
    const int rbase = (l >> 4) * 4;
#pragma unroll
    for (int i = 0; i < 4; i++) {
#pragma unroll
      for (int j = 0; j < 2; j++) {
        int ncol = nb + wc*32 + j*16 + (l & 15);
        float bv = bias[ncol];
#pragma unroll
        for (int r = 0; r < 4; r++) {
          int mrow = mb + wr*64 + i*16 + rbase + r;
          size_t idx = (size_t)mrow * 1024 + ncol;
          outp[idx] = acc[i][j][r] + bv + x[idx];
        }
      }
    }
  }
}

extern "C" void kernel_launch(void* const* d_in, const int* in_sizes, int n_in,
                              void* d_out, int out_size, void* d_ws, size_t ws_size,
                              hipStream_t stream) {
  const float* x     = (const float*)d_in[0];
  const float* gamma = (const float*)d_in[2];
  const float* beta  = (const float*)d_in[3];
  const float* w_in  = (const float*)d_in[4];
  const float* b_in  = (const float*)d_in[5];
  const float* w_out = (const float*)d_in[6];
  const float* b_out = (const float*)d_in[7];
  float* outp = (float*)d_out;                     // [4096][1024]
  float* attw = outp + (size_t)Mm * Dd;            // [2][2048][2048]

  char* ws = (char*)d_ws;
  unsigned short* xn   = (unsigned short*)(ws + 0);          // 8 MB
  unsigned short* wqkv = (unsigned short*)(ws + 8388608);    // 6 MB
  unsigned short* wout = (unsigned short*)(ws + 14680064);   // 2 MB
  unsigned short* qb   = (unsigned short*)(ws + 16777216);   // 8 MB  [b][h][s][hd], pre-scaled 0.125*log2e
  unsigned short* kb   = (unsigned short*)(ws + 25165824);   // 8 MB  [b][h][s][hd]
  unsigned short* vtb  = (unsigned short*)(ws + 33554432);   // 8 MB  [b][h][hd][s]
  float*          linv = (float*)(ws + 41943040);            // 256 KB
  unsigned short* ctxb = (unsigned short*)(ws + 42205184);   // 8 MB  [b][s][d]

  prep_kernel<<<Mm + 1024 + 512, 256, 0, stream>>>(x, gamma, beta, xn, w_in, wqkv, w_out, wout);
  qkv_gemm_kernel<<<(Mm/64)*(N3/128), 256, 0, stream>>>(xn, wqkv, b_in, qb, kb, vtb);
  ctx_kernel<<<dim3(Bb*Hh, Ss/128), 512, 0, stream>>>(qb, kb, vtb, linv, ctxb);
  attnw_out_kernel<<<1536, 256, 0, stream>>>(qb, kb, linv, attw, ctxb, wout, b_out, x, outp);
}